// Round 1
// baseline (1281.992 us; speedup 1.0000x reference)
//
#include <hip/hip_runtime.h>

#define DEV __device__ __forceinline__

// ---------- cross-lane helpers (all VALU, no LDS) ----------

template <int CTRL>
DEV float dppf(float x) {
  return __int_as_float(__builtin_amdgcn_update_dpp(
      0, __float_as_int(x), CTRL, 0xF, 0xF, true));
}

// Butterfly sum over each 32-lane half (lanes l and l+32 hold duplicated data,
// and each half reduces independently; result broadcast to all lanes of the half).
DEV float wsum32(float v) {
  v += dppf<0xB1>(v);   // quad_perm [1,0,3,2]  : xor1
  v += dppf<0x4E>(v);   // quad_perm [2,3,0,1]  : xor2
  v += dppf<0x141>(v);  // row_half_mirror      : xor4 (after quad-uniform)
  v += dppf<0x140>(v);  // row_mirror           : xor8 (after 8-uniform)
#if __has_builtin(__builtin_amdgcn_permlane16_swap)
  {
    auto p = __builtin_amdgcn_permlane16_swap(
        __float_as_uint(v), __float_as_uint(v), false, false);
    v = __uint_as_float(p[0]) + __uint_as_float(p[1]);  // v[l] + v[l^16]
  }
#else
  v += __shfl_xor(v, 16, 64);
#endif
  return v;
}

DEV float wmax32(float v) {
  v = fmaxf(v, dppf<0xB1>(v));
  v = fmaxf(v, dppf<0x4E>(v));
  v = fmaxf(v, dppf<0x141>(v));
  v = fmaxf(v, dppf<0x140>(v));
#if __has_builtin(__builtin_amdgcn_permlane16_swap)
  {
    auto p = __builtin_amdgcn_permlane16_swap(
        __float_as_uint(v), __float_as_uint(v), false, false);
    v = fmaxf(__uint_as_float(p[0]), __uint_as_float(p[1]));
  }
#else
  v = fmaxf(v, __shfl_xor(v, 16, 64));
#endif
  return v;
}

DEV float rlane(float v, int l) {
  return __int_as_float(__builtin_amdgcn_readlane(__float_as_int(v), l));
}

DEV float softmax32(float v) {
  float m = wmax32(v);
  float e = __expf(v - m);
  float s = wsum32(e);
  return __fdividef(e, s);
}

// ---------- main scan kernel: one wave per (b,h) ----------

#define SLEN 1024
#define BSZ 8
#define NH 8
#define DH 32
#define HSTRIDE (BSZ * NH * DH)  // 2048 floats per timestep

__global__ __launch_bounds__(64, 1)
void srwm_scan(const float* __restrict__ h,
               const float* __restrict__ Wy0, const float* __restrict__ Wq0,
               const float* __restrict__ Wk0, const float* __restrict__ wb0,
               float* __restrict__ ys) {
  const int bh   = blockIdx.x;       // 0..63
  const int b    = bh / NH;
  const int hd   = bh % NH;
  const int lane = threadIdx.x;
  const int r    = lane & 31;        // row owned by this lane (duplicated halves)

  // ---- load state: lane holds full row r of each matrix ----
  float Wy[DH], Wq[DH], Wk[DH], wb4[4];
  {
    const float* py = Wy0 + (hd * DH + r) * DH;
    const float* pq = Wq0 + (hd * DH + r) * DH;
    const float* pk = Wk0 + (hd * DH + r) * DH;
#pragma unroll
    for (int c = 0; c < DH; ++c) { Wy[c] = py[c]; Wq[c] = pq[c]; Wk[c] = pk[c]; }
    const float* pb = wb0 + (hd * DH + r) * 4;
#pragma unroll
    for (int k = 0; k < 4; ++k) wb4[k] = pb[k];
  }

  const float* hp = h  + (b * NH + hd) * DH + r;  // h[t][b][hd*32+r]
  float*       yp = ys + (b * NH + hd) * DH;      // ys[t][b][hd*32+..]

  // softmax of first input
  float x = softmax32(hp[0]);

  for (int t = 0; t < SLEN; ++t) {
    // prefetch next h value (hidden under this step's compute)
    float hv_next = (t + 1 < SLEN) ? hp[(t + 1) * HSTRIDE] : 0.f;

    // ---- mat-vecs with x: yt = Wy@x, qp = Wq@x, kp = Wk@x ----
    float aY0 = 0.f, aY1 = 0.f, aQ0 = 0.f, aQ1 = 0.f, aK0 = 0.f, aK1 = 0.f;
#pragma unroll
    for (int j = 0; j < DH; j += 2) {
      float s0 = rlane(x, j);
      float s1 = rlane(x, j + 1);
      aY0 = fmaf(Wy[j], s0, aY0); aY1 = fmaf(Wy[j + 1], s1, aY1);
      aQ0 = fmaf(Wq[j], s0, aQ0); aQ1 = fmaf(Wq[j + 1], s1, aQ1);
      aK0 = fmaf(Wk[j], s0, aK0); aK1 = fmaf(Wk[j + 1], s1, aK1);
    }
    float yt = aY0 + aY1;
    float qp = aQ0 + aQ1;
    float kp = aK0 + aK1;

    // ---- beta pre-activations: bp[k] = sum_i wb[i][k] * x[i] ----
    float bp0 = wsum32(wb4[0] * x);
    float bp1 = wsum32(wb4[1] * x);
    float bp2 = wsum32(wb4[2] * x);
    float bp3 = wsum32(wb4[3] * x);

    // ---- softmaxes (independent chains, interleaved by scheduler) ----
    float q  = softmax32(qp);
    float kt = softmax32(kp);

    float b0 = __fdividef(1.f, 1.f + __expf(-bp0));
    float b1 = __fdividef(1.f, 1.f + __expf(-bp1));
    float b2 = __fdividef(1.f, 1.f + __expf(-bp2));
    float b3 = __fdividef(1.f, 1.f + __expf(-bp3));

    float dvv = q - kt;  // W@q - W@k == W@(q-k)

    // ---- mat-vecs with dvv ----
    float dY0 = 0.f, dY1 = 0.f, dQ0 = 0.f, dQ1 = 0.f, dK0 = 0.f, dK1 = 0.f;
#pragma unroll
    for (int j = 0; j < DH; j += 2) {
      float s0 = rlane(dvv, j);
      float s1 = rlane(dvv, j + 1);
      dY0 = fmaf(Wy[j], s0, dY0); dY1 = fmaf(Wy[j + 1], s1, dY1);
      dQ0 = fmaf(Wq[j], s0, dQ0); dQ1 = fmaf(Wq[j + 1], s1, dQ1);
      dK0 = fmaf(Wk[j], s0, dK0); dK1 = fmaf(Wk[j + 1], s1, dK1);
    }
    float dy = dY0 + dY1;
    float dq = dQ0 + dQ1;
    float dk = dK0 + dK1;

    float db0 = wsum32(wb4[0] * dvv);
    float db1 = wsum32(wb4[1] * dvv);
    float db2 = wsum32(wb4[2] * dvv);
    float db3 = wsum32(wb4[3] * dvv);

    // ---- softmax of next input: independent chain, overlaps updates ----
    float x_next = softmax32(hv_next);

    // ---- rank-1 updates: W[r][c] += (bt * d[r]) * kt[c] ----
    float cY = b0 * dy, cQ = b1 * dq, cK = b2 * dk;
#pragma unroll
    for (int c = 0; c < DH; ++c) {
      float kc = rlane(kt, c);
      Wy[c] = fmaf(cY, kc, Wy[c]);
      Wq[c] = fmaf(cQ, kc, Wq[c]);
      Wk[c] = fmaf(cK, kc, Wk[c]);
    }
    // wb[r][k] += b3 * kt[r] * db[k]
    float bk = b3 * kt;
    wb4[0] = fmaf(bk, db0, wb4[0]);
    wb4[1] = fmaf(bk, db1, wb4[1]);
    wb4[2] = fmaf(bk, db2, wb4[2]);
    wb4[3] = fmaf(bk, db3, wb4[3]);

    // ---- emit yt ----
    if (lane < DH) yp[t * HSTRIDE + lane] = yt;

    x = x_next;
  }
}

// ---------- projection: out = h + ys @ Wout^T  (in-place over ys==out) ----------

__global__ __launch_bounds__(256)
void srwm_proj(const float* __restrict__ h, const float* __restrict__ ys,
               const float* __restrict__ Wout, float* __restrict__ out) {
  __shared__ float ytile[32][256];  // 32 KB
  const int r0  = blockIdx.x * 32;  // 32 (t,b) rows per block
  const int tid = threadIdx.x;

  // cooperative load of the 32 rows this block will overwrite
  const float4* src = (const float4*)(ys + (size_t)r0 * 256);
  float4*       dst = (float4*)(&ytile[0][0]);
#pragma unroll
  for (int i = 0; i < 8; ++i) dst[tid + i * 256] = src[tid + i * 256];
  __syncthreads();

  float acc[32];
#pragma unroll
  for (int m = 0; m < 32; ++m) acc[m] = 0.f;

  const float* wrow = Wout + (size_t)tid * 256;  // output column = tid
  for (int k = 0; k < 256; k += 4) {
    float4 w = *(const float4*)(wrow + k);
#pragma unroll
    for (int m = 0; m < 32; ++m) {
      float4 y4 = *(const float4*)(&ytile[m][k]);  // uniform addr -> broadcast
      acc[m] = fmaf(w.x, y4.x,
               fmaf(w.y, y4.y,
               fmaf(w.z, y4.z,
               fmaf(w.w, y4.w, acc[m]))));
    }
  }

#pragma unroll
  for (int m = 0; m < 32; ++m) {
    int row = r0 + m;
    out[(size_t)row * 256 + tid] = h[(size_t)row * 256 + tid] + acc[m];
  }
}

// ---------- launcher ----------

extern "C" void kernel_launch(void* const* d_in, const int* in_sizes, int n_in,
                              void* d_out, int out_size, void* d_ws, size_t ws_size,
                              hipStream_t stream) {
  const float* h    = (const float*)d_in[0];
  const float* Wy0  = (const float*)d_in[1];
  const float* Wq0  = (const float*)d_in[2];
  const float* Wk0  = (const float*)d_in[3];
  const float* wb0  = (const float*)d_in[4];
  const float* Wout = (const float*)d_in[5];
  float* out = (float*)d_out;

  // Stage ys in d_out itself: scan fully overwrites it; projection reads each
  // 32-row tile into LDS before overwriting those same rows (in-place safe).
  float* ys = out;

  srwm_scan<<<64, 64, 0, stream>>>(h, Wy0, Wq0, Wk0, wb0, ys);
  srwm_proj<<<256, 256, 0, stream>>>(h, ys, Wout, out);
}

// Round 2
// 849.331 us; speedup vs baseline: 1.5094x; 1.5094x over previous
//
#include <hip/hip_runtime.h>

#define DEV __device__ __forceinline__

// ---------- cross-lane helpers (all VALU, no LDS) ----------

template <int CTRL>
DEV float dppf(float x) {
  return __int_as_float(__builtin_amdgcn_update_dpp(
      0, __float_as_int(x), CTRL, 0xF, 0xF, true));
}

// Butterfly sum within each 32-lane half (halves hold identical data here);
// result broadcast to all lanes.
DEV float wsum32(float v) {
  v += dppf<0xB1>(v);   // xor1
  v += dppf<0x4E>(v);   // xor2
  v += dppf<0x141>(v);  // xor4 (row_half_mirror)
  v += dppf<0x140>(v);  // xor8 (row_mirror)
#if __has_builtin(__builtin_amdgcn_permlane16_swap)
  {
    auto p = __builtin_amdgcn_permlane16_swap(
        __float_as_uint(v), __float_as_uint(v), false, false);
    v = __uint_as_float(p[0]) + __uint_as_float(p[1]);  // v[l] + v[l^16]
  }
#else
  v += __shfl_xor(v, 16, 64);
#endif
  return v;
}

// v[l] + v[l^32] for every lane (combine the two half-row partial dots).
DEV float halfsum(float v) {
#if __has_builtin(__builtin_amdgcn_permlane32_swap)
  auto p = __builtin_amdgcn_permlane32_swap(
      __float_as_uint(v), __float_as_uint(v), false, false);
  return __uint_as_float(p[0]) + __uint_as_float(p[1]);
#else
  return v + __shfl_xor(v, 32, 64);
#endif
}

DEV float rlane(float v, int l) {
  return __int_as_float(__builtin_amdgcn_readlane(__float_as_int(v), l));
}

// ---------- main scan kernel: one wave per (b,h) ----------

#define SLEN 1024
#define BSZ 8
#define NH 8
#define DH 32
#define HSTRIDE (BSZ * NH * DH)  // 2048 floats per timestep

__global__ __launch_bounds__(64, 1)
void srwm_scan(const float* __restrict__ h,
               const float* __restrict__ Wy0, const float* __restrict__ Wq0,
               const float* __restrict__ Wk0, const float* __restrict__ wb0,
               float* __restrict__ ys) {
  __shared__ float xs[2][DH];  // softmaxed input, double-buffered by parity
  __shared__ float dvs[DH];    // dvv = q - k
  __shared__ float kvs[DH];    // kt

  const int bh   = blockIdx.x;  // 0..63
  const int b    = bh / NH;
  const int hd   = bh % NH;
  const int lane = threadIdx.x;
  const int r    = lane & 31;         // row owned by this lane
  const int c0   = (lane >> 5) * 16;  // column-chunk start (0 or 16)
  const int kk   = r & 3;             // wb column owned (duplicated over r>=4)

  // ---- state: lane holds cols c0..c0+15 of row r of each W; and wb^T chunk ----
  float Wy[16], Wq[16], Wk[16], WB[16];
  {
    const float* py = Wy0 + (hd * DH + r) * DH + c0;
    const float* pq = Wq0 + (hd * DH + r) * DH + c0;
    const float* pk = Wk0 + (hd * DH + r) * DH + c0;
#pragma unroll
    for (int j = 0; j < 16; j += 4) {
      *(float4*)&Wy[j] = *(const float4*)(py + j);
      *(float4*)&Wq[j] = *(const float4*)(pq + j);
      *(float4*)&Wk[j] = *(const float4*)(pk + j);
    }
    // WB[j] = wb[c0+j][kk]  (wb^T chunk: reduction over rows becomes a chunk dot)
#pragma unroll
    for (int j = 0; j < 16; ++j) WB[j] = wb0[(hd * DH + c0 + j) * 4 + kk];
  }

  const float* hp = h  + (b * NH + hd) * DH + r;
  float*       yp = ys + (b * NH + hd) * DH;

  // ---- x0 = softmax(h[0]) (no max-subtract; inputs bounded) ----
  {
    float e = __expf(hp[0]);
    float x0 = __fdividef(e, wsum32(e));
    if (lane < DH) xs[0][lane] = x0;
  }

  for (int t = 0; t < SLEN; ++t) {
    const int p  = t & 1;
    const int tn = (t + 1 < SLEN) ? (t + 1) : t;
    float hv_next = hp[tn * HSTRIDE];  // issued early, consumed late

    // ---- x chunk (uniform-per-half LDS broadcast reads) ----
    float xv[16];
    *(float4*)&xv[0]  = *(const float4*)&xs[p][c0];
    *(float4*)&xv[4]  = *(const float4*)&xs[p][c0 + 4];
    *(float4*)&xv[8]  = *(const float4*)&xs[p][c0 + 8];
    *(float4*)&xv[12] = *(const float4*)&xs[p][c0 + 12];

    // ---- mat-vecs with x: yt, qp, kp, bp (4 matrices share the chunk) ----
    float aY0 = 0.f, aY1 = 0.f, aQ0 = 0.f, aQ1 = 0.f;
    float aK0 = 0.f, aK1 = 0.f, aB0 = 0.f, aB1 = 0.f;
#pragma unroll
    for (int j = 0; j < 16; j += 2) {
      aY0 = fmaf(Wy[j], xv[j], aY0); aY1 = fmaf(Wy[j + 1], xv[j + 1], aY1);
      aQ0 = fmaf(Wq[j], xv[j], aQ0); aQ1 = fmaf(Wq[j + 1], xv[j + 1], aQ1);
      aK0 = fmaf(Wk[j], xv[j], aK0); aK1 = fmaf(Wk[j + 1], xv[j + 1], aK1);
      aB0 = fmaf(WB[j], xv[j], aB0); aB1 = fmaf(WB[j + 1], xv[j + 1], aB1);
    }
    float yt = halfsum(aY0 + aY1);
    float qp = halfsum(aQ0 + aQ1);
    float kp = halfsum(aK0 + aK1);
    float bp = halfsum(aB0 + aB1);  // lane r holds bp[r&3]

    // ---- sigmoid betas; broadcast the 4 scalars ----
    float bs = __fdividef(1.f, 1.f + __expf(-bp));
    float b0 = rlane(bs, 0), b1 = rlane(bs, 1), b2 = rlane(bs, 2), b3 = rlane(bs, 3);

    // ---- softmaxes (no max-subtract; two independent chains) ----
    float eq = __expf(qp);
    float q  = __fdividef(eq, wsum32(eq));
    float ek = __expf(kp);
    float kt = __fdividef(ek, wsum32(ek));
    float dv = q - kt;

    if (lane < DH) {
      dvs[lane] = dv;
      kvs[lane] = kt;
      yp[t * HSTRIDE + lane] = yt;
    }

    // ---- dvv & kt chunks ----
    float dl[16], kl[16];
    *(float4*)&dl[0]  = *(const float4*)&dvs[c0];
    *(float4*)&dl[4]  = *(const float4*)&dvs[c0 + 4];
    *(float4*)&dl[8]  = *(const float4*)&dvs[c0 + 8];
    *(float4*)&dl[12] = *(const float4*)&dvs[c0 + 12];
    *(float4*)&kl[0]  = *(const float4*)&kvs[c0];
    *(float4*)&kl[4]  = *(const float4*)&kvs[c0 + 4];
    *(float4*)&kl[8]  = *(const float4*)&kvs[c0 + 8];
    *(float4*)&kl[12] = *(const float4*)&kvs[c0 + 12];

    // ---- mat-vecs with dvv: dy, dq, dk, db ----
    float dY0 = 0.f, dY1 = 0.f, dQ0 = 0.f, dQ1 = 0.f;
    float dK0 = 0.f, dK1 = 0.f, dB0 = 0.f, dB1 = 0.f;
#pragma unroll
    for (int j = 0; j < 16; j += 2) {
      dY0 = fmaf(Wy[j], dl[j], dY0); dY1 = fmaf(Wy[j + 1], dl[j + 1], dY1);
      dQ0 = fmaf(Wq[j], dl[j], dQ0); dQ1 = fmaf(Wq[j + 1], dl[j + 1], dQ1);
      dK0 = fmaf(Wk[j], dl[j], dK0); dK1 = fmaf(Wk[j + 1], dl[j + 1], dK1);
      dB0 = fmaf(WB[j], dl[j], dB0); dB1 = fmaf(WB[j + 1], dl[j + 1], dB1);
    }
    float dy  = halfsum(dY0 + dY1);
    float dq  = halfsum(dQ0 + dQ1);
    float dk  = halfsum(dK0 + dK1);
    float dbv = halfsum(dB0 + dB1);  // lane r holds db[r&3]

    // ---- next input softmax (independent chain, overlaps updates) ----
    float en = __expf(hv_next);
    float xn = __fdividef(en, wsum32(en));
    if (lane < DH) xs[p ^ 1][lane] = xn;

    // ---- rank-1 updates: W[r][c] += (b * d[r]) * kt[c] over the chunk ----
    float cY = b0 * dy, cQ = b1 * dq, cK = b2 * dk, cB = b3 * dbv;
#pragma unroll
    for (int j = 0; j < 16; ++j) {
      Wy[j] = fmaf(cY, kl[j], Wy[j]);
      Wq[j] = fmaf(cQ, kl[j], Wq[j]);
      Wk[j] = fmaf(cK, kl[j], Wk[j]);
      WB[j] = fmaf(cB, kl[j], WB[j]);
    }
  }
}

// ---------- projection: out = h + ys @ Wout^T  (in-place over ys==out) ----------

__global__ __launch_bounds__(256)
void srwm_proj(const float* __restrict__ h, const float* __restrict__ ys,
               const float* __restrict__ Wout, float* __restrict__ out) {
  __shared__ float ytile[32][256];  // 32 KB
  const int r0  = blockIdx.x * 32;  // 32 (t,b) rows per block
  const int tid = threadIdx.x;

  const float4* src = (const float4*)(ys + (size_t)r0 * 256);
  float4*       dst = (float4*)(&ytile[0][0]);
#pragma unroll
  for (int i = 0; i < 8; ++i) dst[tid + i * 256] = src[tid + i * 256];
  __syncthreads();

  float acc[32];
#pragma unroll
  for (int m = 0; m < 32; ++m) acc[m] = 0.f;

  const float* wrow = Wout + (size_t)tid * 256;  // output column = tid
  for (int k = 0; k < 256; k += 4) {
    float4 w = *(const float4*)(wrow + k);
#pragma unroll
    for (int m = 0; m < 32; ++m) {
      float4 y4 = *(const float4*)(&ytile[m][k]);  // uniform addr -> broadcast
      acc[m] = fmaf(w.x, y4.x,
               fmaf(w.y, y4.y,
               fmaf(w.z, y4.z,
               fmaf(w.w, y4.w, acc[m]))));
    }
  }

#pragma unroll
  for (int m = 0; m < 32; ++m) {
    int row = r0 + m;
    out[(size_t)row * 256 + tid] = h[(size_t)row * 256 + tid] + acc[m];
  }
}

// ---------- launcher ----------

extern "C" void kernel_launch(void* const* d_in, const int* in_sizes, int n_in,
                              void* d_out, int out_size, void* d_ws, size_t ws_size,
                              hipStream_t stream) {
  const float* h    = (const float*)d_in[0];
  const float* Wy0  = (const float*)d_in[1];
  const float* Wq0  = (const float*)d_in[2];
  const float* Wk0  = (const float*)d_in[3];
  const float* wb0  = (const float*)d_in[4];
  const float* Wout = (const float*)d_in[5];
  float* out = (float*)d_out;

  float* ys = out;  // scan fully overwrites d_out; projection is in-place safe

  srwm_scan<<<64, 64, 0, stream>>>(h, Wy0, Wq0, Wk0, wb0, ys);
  srwm_proj<<<256, 256, 0, stream>>>(h, ys, Wout, out);
}

// Round 3
// 748.309 us; speedup vs baseline: 1.7132x; 1.1350x over previous
//
#include <hip/hip_runtime.h>

#define DEV __device__ __forceinline__

// ---------- cross-lane helpers (all VALU, no LDS) ----------

template <int CTRL>
DEV float dppf(float x) {
  return __int_as_float(__builtin_amdgcn_update_dpp(
      0, __float_as_int(x), CTRL, 0xF, 0xF, true));
}

// Butterfly sum within each 32-lane half; result broadcast to all lanes of the half.
DEV float wsum32(float v) {
  v += dppf<0xB1>(v);   // xor1
  v += dppf<0x4E>(v);   // xor2
  v += dppf<0x141>(v);  // xor4 (row_half_mirror)
  v += dppf<0x140>(v);  // xor8 (row_mirror)
#if __has_builtin(__builtin_amdgcn_permlane16_swap)
  {
    auto p = __builtin_amdgcn_permlane16_swap(
        __float_as_uint(v), __float_as_uint(v), false, false);
    v = __uint_as_float(p[0]) + __uint_as_float(p[1]);  // v[l] + v[l^16]
  }
#else
  v += __shfl_xor(v, 16, 64);
#endif
  return v;
}

// v[l] + v[l^32] (combine the two half-row partial dots).
DEV float halfsum(float v) {
#if __has_builtin(__builtin_amdgcn_permlane32_swap)
  auto p = __builtin_amdgcn_permlane32_swap(
      __float_as_uint(v), __float_as_uint(v), false, false);
  return __uint_as_float(p[0]) + __uint_as_float(p[1]);
#else
  return v + __shfl_xor(v, 32, 64);
#endif
}

DEV float rlane(float v, int l) {
  return __int_as_float(__builtin_amdgcn_readlane(__float_as_int(v), l));
}

#define SLEN 1024
#define NH 8
#define DH 32
#define HSTRIDE 2048  // floats per timestep (B*NH*DH)

// ---------- phase 1: x = softmax32(h), staged into d_out ----------

__global__ __launch_bounds__(256)
void srwm_xsm(const float* __restrict__ h, float* __restrict__ x) {
  int i = blockIdx.x * 256 + threadIdx.x;
  float e = __expf(h[i]);
  x[i] = __fdividef(e, wsum32(e));  // 32-groups align with lane halves
}

// ---------- phase 2: the scan. One wave per (b,h). ----------
// xy = d_out: holds x on entry; y_t overwrites position t (read front stays ahead).

#define MATVEC4(o0, o1, o2, o3, V)                                         \
  {                                                                        \
    float a0 = 0.f, a1 = 0.f, b0 = 0.f, b1 = 0.f;                          \
    float e0 = 0.f, e1 = 0.f, f0 = 0.f, f1 = 0.f;                          \
    _Pragma("unroll") for (int j = 0; j < 16; j += 2) {                    \
      a0 = fmaf(Wy[j], V[j], a0); a1 = fmaf(Wy[j + 1], V[j + 1], a1);      \
      b0 = fmaf(Wq[j], V[j], b0); b1 = fmaf(Wq[j + 1], V[j + 1], b1);      \
      e0 = fmaf(Wk[j], V[j], e0); e1 = fmaf(Wk[j + 1], V[j + 1], e1);      \
      f0 = fmaf(WB[j], V[j], f0); f1 = fmaf(WB[j + 1], V[j + 1], f1);      \
    }                                                                      \
    o0 = halfsum(a0 + a1); o1 = halfsum(b0 + b1);                          \
    o2 = halfsum(e0 + e1); o3 = halfsum(f0 + f1);                          \
  }

// One scan step. On entry: (yA,qpA,kpA,bpA) = a_t = W_t x_t ; W regs = W_{t-1};
// XC = x_{t+1} chunks; xsS = x_{t+1}[r]; (uY..uB, kvs[PAR^1]) = u_{t-1}, k_{t-1}.
#define STEP(t, PAR, XC, XN)                                               \
  {                                                                        \
    /* k_{t-1} chunks (written last step; off-path) */                     \
    float klP[16];                                                         \
    _Pragma("unroll") for (int j = 0; j < 16; j += 4)                      \
      *(float4*)&klP[j] = *(const float4*)(&kvs[(PAR) ^ 1][c0 + j]);       \
    /* prefetch x_{t+2} chunks + scalar (consumed next step) */            \
    int t2 = (t) + 2; if (t2 > SLEN - 1) t2 = SLEN - 1;                    \
    _Pragma("unroll") for (int j = 0; j < 16; j += 4)                      \
      *(float4*)&XN[j] = *(const float4*)(xb + t2 * HSTRIDE + c0 + j);     \
    float xsN = xb[t2 * HSTRIDE + r];                                      \
    /* emit y_t (position t is behind the read front) */                   \
    if (lane < DH) xb[(t) * HSTRIDE + lane] = yA;                          \
    /* ---- critical chain: softmax q,k ---- */                            \
    float eq = __expf(qpA), ek = __expf(kpA);                              \
    float q  = __fdividef(eq, wsum32(eq));                                 \
    float kt = __fdividef(ek, wsum32(ek));                                 \
    float dv = q - kt;                                                     \
    dvs[r] = dv;                                                           \
    kvs[PAR][r] = kt;                                                      \
    /* dvv chunks (latency hidden under update+preA below) */              \
    float dl[16];                                                          \
    _Pragma("unroll") for (int j = 0; j < 16; j += 4)                      \
      *(float4*)&dl[j] = *(const float4*)(&dvs[c0 + j]);                   \
    /* betas */                                                            \
    float ebn = __expf(-bpA);                                              \
    float bs  = __fdividef(1.f, 1.f + ebn);                                \
    float B0 = rlane(bs, 0), B1 = rlane(bs, 1);                            \
    float B2 = rlane(bs, 2), B3 = rlane(bs, 3);                            \
    /* materialize W_t = W_{t-1} + u_{t-1} (x) k_{t-1}  (off-path) */      \
    _Pragma("unroll") for (int j = 0; j < 16; ++j) {                       \
      Wy[j] = fmaf(uY, klP[j], Wy[j]);                                     \
      Wq[j] = fmaf(uQ, klP[j], Wq[j]);                                     \
      Wk[j] = fmaf(uK, klP[j], Wk[j]);                                     \
      WB[j] = fmaf(uB, klP[j], WB[j]);                                     \
    }                                                                      \
    /* preA_{t+1} = W_t x_{t+1}  (off-path) */                             \
    float pY, pQ, pK, pB;                                                  \
    MATVEC4(pY, pQ, pK, pB, XC);                                           \
    /* d_t = W_t dvv_t  (on-path tail) */                                  \
    float dY, dQ, dK, dB;                                                  \
    MATVEC4(dY, dQ, dK, dB, dl);                                           \
    /* s_t = k_t . x_{t+1} */                                              \
    float s = wsum32(kt * xsS);                                            \
    /* u_t and a_{t+1} = preA + u_t * s_t */                               \
    uY = B0 * dY; uQ = B1 * dQ; uK = B2 * dK; uB = B3 * dB;                \
    yA  = fmaf(uY, s, pY); qpA = fmaf(uQ, s, pQ);                          \
    kpA = fmaf(uK, s, pK); bpA = fmaf(uB, s, pB);                          \
    xsS = xsN;                                                             \
  }

__global__ __launch_bounds__(64, 1)
void srwm_scan(const float* __restrict__ Wy0, const float* __restrict__ Wq0,
               const float* __restrict__ Wk0, const float* __restrict__ wb0,
               float* xy) {
  __shared__ float dvs[DH];
  __shared__ float kvs[2][DH];

  const int bh   = blockIdx.x;  // 0..63
  const int hd   = bh & 7;
  const int lane = threadIdx.x;
  const int r    = lane & 31;
  const int c0   = (lane >> 5) * 16;
  const int kk   = r & 3;

  // state: lane holds cols c0..c0+15 of row r; WB = wb^T chunk (wb[c0+j][kk])
  float Wy[16], Wq[16], Wk[16], WB[16];
  {
    const float* py = Wy0 + (hd * DH + r) * DH + c0;
    const float* pq = Wq0 + (hd * DH + r) * DH + c0;
    const float* pk = Wk0 + (hd * DH + r) * DH + c0;
#pragma unroll
    for (int j = 0; j < 16; j += 4) {
      *(float4*)&Wy[j] = *(const float4*)(py + j);
      *(float4*)&Wq[j] = *(const float4*)(pq + j);
      *(float4*)&Wk[j] = *(const float4*)(pk + j);
    }
#pragma unroll
    for (int j = 0; j < 16; ++j) WB[j] = wb0[(hd * DH + c0 + j) * 4 + kk];
  }
  if (lane < DH) { kvs[0][lane] = 0.f; kvs[1][lane] = 0.f; }

  float* xb = xy + bh * DH;  // x/y for this (b,h): element [t*HSTRIDE + j]

  float XA[16], XB[16];
  float yA, qpA, kpA, bpA;

  // prologue: a_0 = W_0 x_0 ; then XA <- x_1
#pragma unroll
  for (int j = 0; j < 16; j += 4)
    *(float4*)&XA[j] = *(const float4*)(xb + c0 + j);
  MATVEC4(yA, qpA, kpA, bpA, XA);
#pragma unroll
  for (int j = 0; j < 16; j += 4)
    *(float4*)&XA[j] = *(const float4*)(xb + HSTRIDE + c0 + j);
  float xsS = xb[HSTRIDE + r];
  float uY = 0.f, uQ = 0.f, uK = 0.f, uB = 0.f;

  for (int t = 0; t < SLEN; t += 2) {
    STEP(t, 0, XA, XB);
    STEP(t + 1, 1, XB, XA);
  }
}

// ---------- phase 3: out = h + ys @ Wout^T  (in-place over ys==out) ----------

__global__ __launch_bounds__(256)
void srwm_proj(const float* __restrict__ h, const float* __restrict__ ys,
               const float* __restrict__ Wout, float* __restrict__ out) {
  __shared__ float ytile[32][256];  // 32 KB
  const int r0  = blockIdx.x * 32;
  const int tid = threadIdx.x;

  const float4* src = (const float4*)(ys + (size_t)r0 * 256);
  float4*       dst = (float4*)(&ytile[0][0]);
#pragma unroll
  for (int i = 0; i < 8; ++i) dst[tid + i * 256] = src[tid + i * 256];
  __syncthreads();

  float acc[32];
#pragma unroll
  for (int m = 0; m < 32; ++m) acc[m] = 0.f;

  const float* wrow = Wout + (size_t)tid * 256;
  for (int k = 0; k < 256; k += 4) {
    float4 w = *(const float4*)(wrow + k);
#pragma unroll
    for (int m = 0; m < 32; ++m) {
      float4 y4 = *(const float4*)(&ytile[m][k]);
      acc[m] = fmaf(w.x, y4.x,
               fmaf(w.y, y4.y,
               fmaf(w.z, y4.z,
               fmaf(w.w, y4.w, acc[m]))));
    }
  }

#pragma unroll
  for (int m = 0; m < 32; ++m) {
    int row = r0 + m;
    out[(size_t)row * 256 + tid] = h[(size_t)row * 256 + tid] + acc[m];
  }
}

// ---------- launcher ----------

extern "C" void kernel_launch(void* const* d_in, const int* in_sizes, int n_in,
                              void* d_out, int out_size, void* d_ws, size_t ws_size,
                              hipStream_t stream) {
  const float* h    = (const float*)d_in[0];
  const float* Wy0  = (const float*)d_in[1];
  const float* Wq0  = (const float*)d_in[2];
  const float* Wk0  = (const float*)d_in[3];
  const float* wb0  = (const float*)d_in[4];
  const float* Wout = (const float*)d_in[5];
  float* out = (float*)d_out;

  // d_out triple duty: x (phase1) -> progressively overwritten by y (phase2)
  // -> final output (phase3, in-place via LDS tile).
  srwm_xsm <<<SLEN * HSTRIDE / 256, 256, 0, stream>>>(h, out);
  srwm_scan<<<64, 64, 0, stream>>>(Wy0, Wq0, Wk0, wb0, out);
  srwm_proj<<<256, 256, 0, stream>>>(h, out, Wout, out);
}

// Round 4
// 620.448 us; speedup vs baseline: 2.0662x; 1.2061x over previous
//
#include <hip/hip_runtime.h>

#define DEV __device__ __forceinline__

// ---------- cross-lane helpers (all VALU, no LDS) ----------

template <int CTRL>
DEV float dppf(float x) {
  return __int_as_float(__builtin_amdgcn_update_dpp(
      0, __float_as_int(x), CTRL, 0xF, 0xF, true));
}

// Butterfly sum within each 32-lane half; result broadcast to all lanes of the half.
DEV float wsum32(float v) {
  v += dppf<0xB1>(v);   // xor1
  v += dppf<0x4E>(v);   // xor2
  v += dppf<0x141>(v);  // xor4 (row_half_mirror)
  v += dppf<0x140>(v);  // xor8 (row_mirror)
#if __has_builtin(__builtin_amdgcn_permlane16_swap)
  {
    auto p = __builtin_amdgcn_permlane16_swap(
        __float_as_uint(v), __float_as_uint(v), false, false);
    v = __uint_as_float(p[0]) + __uint_as_float(p[1]);  // v[l] + v[l^16]
  }
#else
  v += __shfl_xor(v, 16, 64);
#endif
  return v;
}

// v[l] + v[l^32] (combine the two half-row partial dots).
DEV float halfsum(float v) {
#if __has_builtin(__builtin_amdgcn_permlane32_swap)
  auto p = __builtin_amdgcn_permlane32_swap(
      __float_as_uint(v), __float_as_uint(v), false, false);
  return __uint_as_float(p[0]) + __uint_as_float(p[1]);
#else
  return v + __shfl_xor(v, 32, 64);
#endif
}

#define SLEN 1024
#define NH 8
#define DH 32
#define HSTRIDE 2048  // floats per timestep (B*NH*DH)

// ---------- phase 1: x = softmax32(h), staged into d_out ----------

__global__ __launch_bounds__(256)
void srwm_xsm(const float* __restrict__ h, float* __restrict__ x) {
  int i = blockIdx.x * 256 + threadIdx.x;
  float e = __expf(h[i]);
  x[i] = __fdividef(e, wsum32(e));  // 32-groups align with lane halves
}

// ---------- phase 2: the scan. One block (4 waves) per (b,h). ----------
// Wave w owns one matrix: 0:Wy 1:Wq 2:Wk 3:wb^T. Lane (r=lane&31, c0) holds
// cols c0..c0+15 of row r (w<3) or wb^T chunk wb[c0+j][r&3] (w==3).
//
// Deferred-update recurrence (identical math to the verified single-wave
// version): entering region R_t each wave holds W = W_{t-1}, preA = W_{t-1}x_t.
//   R_t: read q_{t-1},k_{t-1},B_{t-1} (LDS slot (t-1)&1)
//        dv = q-k ; d = W_{t-1} dv ; s = k_{t-1}.x_t ; u = B*d
//        a_t = preA + u*s          (= W_t x_t)
//        w0: y_t = a_t -> global ; w1/w2: softmax(a_t) -> LDS slot t&1
//        w3: sigmoid(a_t) -> LDS slot t&1
//        W += u (x) k_{t-1}        (= W_t)
//        preA = W_t x_{t+1}
//        barrier (LDS-only: lgkmcnt drain + s_barrier; vmcnt stays in flight)

#define BARRIER() \
  do { asm volatile("s_waitcnt lgkmcnt(0)" ::: "memory"); \
       __builtin_amdgcn_s_barrier(); } while (0)

#define REGION(T, P, XS, XP)                                                  \
  {                                                                           \
    /* q_{T-1}, k_{T-1}, B_{T-1} from slot P^1 (uniform-per-half broadcast) */\
    float ql[16], kl[16];                                                     \
    _Pragma("unroll") for (int j = 0; j < 16; j += 4) {                       \
      *(float4*)&ql[j] = *(const float4*)&qs[(P) ^ 1][c0 + j];                \
      *(float4*)&kl[j] = *(const float4*)&ks2[(P) ^ 1][c0 + j];               \
    }                                                                         \
    float Bw = bss[(P) ^ 1][w];                                               \
    _Pragma("unroll") for (int j = 0; j < 16; ++j) ql[j] -= kl[j];            \
    /* d = W dv  and  s = k . x_t  (independent; interleave) */               \
    float d0 = 0.f, d1 = 0.f, d2 = 0.f, d3 = 0.f, s0 = 0.f, s1 = 0.f;        \
    _Pragma("unroll") for (int j = 0; j < 16; j += 4) {                       \
      d0 = fmaf(W[j],     ql[j],     d0);                                     \
      d1 = fmaf(W[j + 1], ql[j + 1], d1);                                     \
      d2 = fmaf(W[j + 2], ql[j + 2], d2);                                     \
      d3 = fmaf(W[j + 3], ql[j + 3], d3);                                     \
      s0 = fmaf(kl[j],     XS[j],     s0);                                    \
      s1 = fmaf(kl[j + 1], XS[j + 1], s1);                                    \
      s0 = fmaf(kl[j + 2], XS[j + 2], s0);                                    \
      s1 = fmaf(kl[j + 3], XS[j + 3], s1);                                    \
    }                                                                         \
    float dsum = halfsum((d0 + d1) + (d2 + d3));                              \
    float sv   = halfsum(s0 + s1);                                            \
    /* prefetch x_{T+2} into XS (XS dead after s-dot; compiler renames) */    \
    int t2 = (T) + 2; if (t2 > SLEN - 1) t2 = SLEN - 1;                       \
    _Pragma("unroll") for (int j = 0; j < 16; j += 4)                         \
      *(float4*)&XS[j] = *(const float4*)(xb + (size_t)t2 * HSTRIDE + c0 + j);\
    float u  = Bw * dsum;                                                     \
    float aA = fmaf(u, sv, preA);                                             \
    if (w == 0) {                                                             \
      if (lane < DH) xb[(size_t)(T) * HSTRIDE + lane] = aA;  /* y_t */        \
    } else if (w == 1) {                                                      \
      float e = __expf(aA); float qq = __fdividef(e, wsum32(e));              \
      qs[P][r] = qq;        /* 2-way same-addr write: free */                 \
    } else if (w == 2) {                                                      \
      float e = __expf(aA); float kk2 = __fdividef(e, wsum32(e));             \
      ks2[P][r] = kk2;                                                        \
    } else {                                                                  \
      float sg = __fdividef(1.f, 1.f + __expf(-aA));                          \
      if (lane < 4) bss[P][lane] = sg;                                        \
    }                                                                         \
    /* W <- W_T ; then preA = W_T x_{T+1} */                                  \
    _Pragma("unroll") for (int j = 0; j < 16; ++j)                            \
      W[j] = fmaf(u, kl[j], W[j]);                                            \
    float p0 = 0.f, p1 = 0.f, p2 = 0.f, p3 = 0.f;                             \
    _Pragma("unroll") for (int j = 0; j < 16; j += 4) {                       \
      p0 = fmaf(W[j],     XP[j],     p0);                                     \
      p1 = fmaf(W[j + 1], XP[j + 1], p1);                                     \
      p2 = fmaf(W[j + 2], XP[j + 2], p2);                                     \
      p3 = fmaf(W[j + 3], XP[j + 3], p3);                                     \
    }                                                                         \
    preA = halfsum((p0 + p1) + (p2 + p3));                                    \
    BARRIER();                                                                \
  }

__global__ __launch_bounds__(256, 1)
void srwm_scan(const float* __restrict__ Wy0, const float* __restrict__ Wq0,
               const float* __restrict__ Wk0, const float* __restrict__ wb0,
               float* xy) {
  __shared__ float qs[2][DH];
  __shared__ float ks2[2][DH];
  __shared__ float bss[2][4];

  const int bh   = blockIdx.x;        // 0..63
  const int hd   = bh & 7;
  const int w    = threadIdx.x >> 6;  // wave: 0..3
  const int lane = threadIdx.x & 63;
  const int r    = lane & 31;
  const int c0   = (lane >> 5) * 16;

  // ---- load this wave's matrix ----
  float W[16];
  if (w < 3) {
    const float* src = (w == 0) ? Wy0 : (w == 1) ? Wq0 : Wk0;
    const float* p = src + (hd * DH + r) * DH + c0;
#pragma unroll
    for (int j = 0; j < 16; j += 4) *(float4*)&W[j] = *(const float4*)(p + j);
  } else {
    const int kk = r & 3;
#pragma unroll
    for (int j = 0; j < 16; ++j) W[j] = wb0[(hd * DH + c0 + j) * 4 + kk];
  }

  // zero the t=-1 slot (slot 1): q=k=0 -> d=0 -> u=0; B value irrelevant
  if (threadIdx.x < DH) { qs[1][threadIdx.x] = 0.f; ks2[1][threadIdx.x] = 0.f; }
  if (threadIdx.x < 4)  { bss[1][threadIdx.x] = 0.f; bss[0][threadIdx.x] = 0.f; }

  float* xb = xy + bh * DH;  // x/y for this (b,h): element [t*HSTRIDE + j]

  // ---- prologue: X0 <- x_0, X1 <- x_1, preA = W_0 x_0 ----
  float X0[16], X1[16];
#pragma unroll
  for (int j = 0; j < 16; j += 4) {
    *(float4*)&X0[j] = *(const float4*)(xb + c0 + j);
    *(float4*)&X1[j] = *(const float4*)(xb + HSTRIDE + c0 + j);
  }
  float p0 = 0.f, p1 = 0.f, p2 = 0.f, p3 = 0.f;
#pragma unroll
  for (int j = 0; j < 16; j += 4) {
    p0 = fmaf(W[j],     X0[j],     p0);
    p1 = fmaf(W[j + 1], X0[j + 1], p1);
    p2 = fmaf(W[j + 2], X0[j + 2], p2);
    p3 = fmaf(W[j + 3], X0[j + 3], p3);
  }
  float preA = halfsum((p0 + p1) + (p2 + p3));
  __syncthreads();

  for (int t = 0; t < SLEN; t += 2) {
    REGION(t,     0, X0, X1);
    REGION(t + 1, 1, X1, X0);
  }
}

// ---------- phase 3: out = h + ys @ Wout^T  (in-place over ys==out) ----------

__global__ __launch_bounds__(256)
void srwm_proj(const float* __restrict__ h, const float* __restrict__ ys,
               const float* __restrict__ Wout, float* __restrict__ out) {
  __shared__ float ytile[32][256];  // 32 KB
  const int r0  = blockIdx.x * 32;
  const int tid = threadIdx.x;

  const float4* src = (const float4*)(ys + (size_t)r0 * 256);
  float4*       dst = (float4*)(&ytile[0][0]);
#pragma unroll
  for (int i = 0; i < 8; ++i) dst[tid + i * 256] = src[tid + i * 256];
  __syncthreads();

  float acc[32];
#pragma unroll
  for (int m = 0; m < 32; ++m) acc[m] = 0.f;

  const float* wrow = Wout + (size_t)tid * 256;
  for (int k = 0; k < 256; k += 4) {
    float4 w = *(const float4*)(wrow + k);
#pragma unroll
    for (int m = 0; m < 32; ++m) {
      float4 y4 = *(const float4*)(&ytile[m][k]);
      acc[m] = fmaf(w.x, y4.x,
               fmaf(w.y, y4.y,
               fmaf(w.z, y4.z,
               fmaf(w.w, y4.w, acc[m]))));
    }
  }

#pragma unroll
  for (int m = 0; m < 32; ++m) {
    int row = r0 + m;
    out[(size_t)row * 256 + tid] = h[(size_t)row * 256 + tid] + acc[m];
  }
}

// ---------- launcher ----------

extern "C" void kernel_launch(void* const* d_in, const int* in_sizes, int n_in,
                              void* d_out, int out_size, void* d_ws, size_t ws_size,
                              hipStream_t stream) {
  const float* h    = (const float*)d_in[0];
  const float* Wy0  = (const float*)d_in[1];
  const float* Wq0  = (const float*)d_in[2];
  const float* Wk0  = (const float*)d_in[3];
  const float* wb0  = (const float*)d_in[4];
  const float* Wout = (const float*)d_in[5];
  float* out = (float*)d_out;

  // d_out triple duty: x (phase1) -> progressively overwritten by y (phase2)
  // -> final output (phase3, in-place via LDS tile).
  srwm_xsm <<<SLEN * HSTRIDE / 256, 256, 0, stream>>>(h, out);
  srwm_scan<<<64, 256, 0, stream>>>(Wy0, Wq0, Wk0, wb0, out);
  srwm_proj<<<256, 256, 0, stream>>>(h, out, Wout, out);
}

// Round 5
// 571.229 us; speedup vs baseline: 2.2443x; 1.0862x over previous
//
#include <hip/hip_runtime.h>

#define DEV __device__ __forceinline__

// ---------- cross-lane helpers (all VALU, no LDS) ----------

template <int CTRL>
DEV float dppf(float x) {
  return __int_as_float(__builtin_amdgcn_update_dpp(
      0, __float_as_int(x), CTRL, 0xF, 0xF, true));
}

// Butterfly sum within each 32-lane half; result broadcast to all lanes of the half.
DEV float wsum32(float v) {
  v += dppf<0xB1>(v);   // xor1
  v += dppf<0x4E>(v);   // xor2
  v += dppf<0x141>(v);  // xor4 (row_half_mirror)
  v += dppf<0x140>(v);  // xor8 (row_mirror)
#if __has_builtin(__builtin_amdgcn_permlane16_swap)
  {
    auto p = __builtin_amdgcn_permlane16_swap(
        __float_as_uint(v), __float_as_uint(v), false, false);
    v = __uint_as_float(p[0]) + __uint_as_float(p[1]);  // v[l] + v[l^16]
  }
#else
  v += __shfl_xor(v, 16, 64);
#endif
  return v;
}

// v[l] + v[l^32] (combine the two half-row partial dots).
DEV float halfsum(float v) {
#if __has_builtin(__builtin_amdgcn_permlane32_swap)
  auto p = __builtin_amdgcn_permlane32_swap(
      __float_as_uint(v), __float_as_uint(v), false, false);
  return __uint_as_float(p[0]) + __uint_as_float(p[1]);
#else
  return v + __shfl_xor(v, 32, 64);
#endif
}

#define SLEN 1024
#define NH 8
#define DH 32
#define HSTRIDE 2048  // floats per timestep (B*NH*DH)

// ---------- phase 1: x = softmax32(h), staged into d_out ----------

__global__ __launch_bounds__(256)
void srwm_xsm(const float* __restrict__ h, float* __restrict__ x) {
  int i = blockIdx.x * 256 + threadIdx.x;
  float e = __expf(h[i]);
  x[i] = __fdividef(e, wsum32(e));  // 32-groups align with lane halves
}

// ---------- phase 2: the scan. One block (4 waves) per (b,h). ----------
// Wave w owns one matrix: 0:Wy 1:Wq 2:Wk 3:wb^T. Lane (r=lane&31, c0) holds
// cols c0..c0+15 of row r (w<3) or wb^T chunk wb[c0+j][r&3] (w==3).
//
// Deferred-update recurrence (identical math to R4, rescheduled):
// entering region T: regs hold q_{T-1},k_{T-1} chunks (QV,KV), B_{T-1}[w] (BW);
// W = W_{T-1}; preA = W_{T-1} x_T.
//   pre-barrier : dv=q-k ; d=W dv ; s=k.x_T ; u=BW*d ; a_T=preA+u*s
//                 w0: y_T->global ; w1/w2: softmax(a_T)->slot P ; w3: sigmoid->slot P
//                 lgkm drain ; s_barrier
//   post-barrier: LDS reads of slot P (q_T,k_T,B_T -> QN,KN,BN)   [latency...]
//                 W += u (x) k_{T-1} ; prefetch x_{T+2} ; preA = W_T x_{T+1}
//                 [...hidden under the reads' latency]

#define BARRIER() \
  do { asm volatile("s_waitcnt lgkmcnt(0)" ::: "memory"); \
       __builtin_amdgcn_s_barrier(); } while (0)

#define REGION(T, P, QV, KV, BW, QN, KN, BN, XS, XP)                          \
  {                                                                           \
    /* ---- on-path: dv, d-matvec + s-dot (interleaved), u, a_T ---- */       \
    float dv[16];                                                             \
    _Pragma("unroll") for (int j = 0; j < 16; ++j) dv[j] = QV[j] - KV[j];     \
    float d0 = 0.f, d1 = 0.f, d2 = 0.f, d3 = 0.f, s0 = 0.f, s1 = 0.f;         \
    _Pragma("unroll") for (int j = 0; j < 16; j += 4) {                       \
      d0 = fmaf(W[j],     dv[j],     d0);                                     \
      d1 = fmaf(W[j + 1], dv[j + 1], d1);                                     \
      d2 = fmaf(W[j + 2], dv[j + 2], d2);                                     \
      d3 = fmaf(W[j + 3], dv[j + 3], d3);                                     \
      s0 = fmaf(KV[j],     XS[j],     s0);                                    \
      s1 = fmaf(KV[j + 1], XS[j + 1], s1);                                    \
      s0 = fmaf(KV[j + 2], XS[j + 2], s0);                                    \
      s1 = fmaf(KV[j + 3], XS[j + 3], s1);                                    \
    }                                                                         \
    float dsum = halfsum((d0 + d1) + (d2 + d3));                              \
    float sv   = halfsum(s0 + s1);                                            \
    float u  = BW * dsum;                                                     \
    float aA = fmaf(u, sv, preA);                                             \
    if (w == 0) {                                                             \
      if (lane < DH) xb[(size_t)(T) * HSTRIDE + lane] = aA;  /* y_T */        \
    } else if (w == 1) {                                                      \
      float e = __expf(aA); qs[P][r] = __fdividef(e, wsum32(e));              \
    } else if (w == 2) {                                                      \
      float e = __expf(aA); ks2[P][r] = __fdividef(e, wsum32(e));             \
    } else {                                                                  \
      float sg = __fdividef(1.f, 1.f + __expf(-aA));                          \
      if (lane < 4) bss[P][lane] = sg;                                        \
    }                                                                         \
    BARRIER();                                                                \
    /* ---- post-barrier: reads first (latency), reg-work under them ---- */  \
    _Pragma("unroll") for (int j = 0; j < 16; j += 4) {                       \
      *(float4*)&QN[j] = *(const float4*)&qs[P][c0 + j];                      \
      *(float4*)&KN[j] = *(const float4*)&ks2[P][c0 + j];                     \
    }                                                                         \
    BN = bss[P][w];                                                           \
    /* W <- W_T (uses OLD k = KV) */                                          \
    _Pragma("unroll") for (int j = 0; j < 16; ++j)                            \
      W[j] = fmaf(u, KV[j], W[j]);                                            \
    /* prefetch x_{T+2} into XS (XS consumed above; compiler renames) */      \
    int t2 = (T) + 2; if (t2 > SLEN - 1) t2 = SLEN - 1;                       \
    _Pragma("unroll") for (int j = 0; j < 16; j += 4)                         \
      *(float4*)&XS[j] = *(const float4*)(xb + (size_t)t2 * HSTRIDE + c0 + j);\
    /* preA = W_T x_{T+1} */                                                  \
    float p0 = 0.f, p1 = 0.f, p2 = 0.f, p3 = 0.f;                             \
    _Pragma("unroll") for (int j = 0; j < 16; j += 4) {                       \
      p0 = fmaf(W[j],     XP[j],     p0);                                     \
      p1 = fmaf(W[j + 1], XP[j + 1], p1);                                     \
      p2 = fmaf(W[j + 2], XP[j + 2], p2);                                     \
      p3 = fmaf(W[j + 3], XP[j + 3], p3);                                     \
    }                                                                         \
    preA = halfsum((p0 + p1) + (p2 + p3));                                    \
  }

__global__ __launch_bounds__(256, 1)
void srwm_scan(const float* __restrict__ Wy0, const float* __restrict__ Wq0,
               const float* __restrict__ Wk0, const float* __restrict__ wb0,
               float* xy) {
  __shared__ float qs[2][DH];
  __shared__ float ks2[2][DH];
  __shared__ float bss[2][4];

  const int bh   = blockIdx.x;        // 0..63
  const int hd   = bh & 7;
  const int w    = threadIdx.x >> 6;  // wave: 0..3
  const int lane = threadIdx.x & 63;
  const int r    = lane & 31;
  const int c0   = (lane >> 5) * 16;

  // ---- load this wave's matrix ----
  float W[16];
  if (w < 3) {
    const float* src = (w == 0) ? Wy0 : (w == 1) ? Wq0 : Wk0;
    const float* p = src + (hd * DH + r) * DH + c0;
#pragma unroll
    for (int j = 0; j < 16; j += 4) *(float4*)&W[j] = *(const float4*)(p + j);
  } else {
    const int kk = r & 3;
#pragma unroll
    for (int j = 0; j < 16; ++j) W[j] = wb0[(hd * DH + c0 + j) * 4 + kk];
  }

  float* xb = xy + bh * DH;  // x/y for this (b,h): element [t*HSTRIDE + j]

  // ---- prologue: X0 <- x_0, X1 <- x_1; q_{-1}=k_{-1}=0, B_{-1}=0 in regs;
  //      preA = W_0 x_0 (u_{-1}=0 so W_{-1} == W_0) ----
  float X0[16], X1[16];
#pragma unroll
  for (int j = 0; j < 16; j += 4) {
    *(float4*)&X0[j] = *(const float4*)(xb + c0 + j);
    *(float4*)&X1[j] = *(const float4*)(xb + HSTRIDE + c0 + j);
  }
  float p0 = 0.f, p1 = 0.f, p2 = 0.f, p3 = 0.f;
#pragma unroll
  for (int j = 0; j < 16; j += 4) {
    p0 = fmaf(W[j],     X0[j],     p0);
    p1 = fmaf(W[j + 1], X0[j + 1], p1);
    p2 = fmaf(W[j + 2], X0[j + 2], p2);
    p3 = fmaf(W[j + 3], X0[j + 3], p3);
  }
  float preA = halfsum((p0 + p1) + (p2 + p3));

  float QA[16], KA[16], QB[16], KB[16];
#pragma unroll
  for (int j = 0; j < 16; ++j) { QA[j] = 0.f; KA[j] = 0.f; }
  float BwA = 0.f, BwB = 0.f;

  __syncthreads();

  for (int t = 0; t < SLEN; t += 2) {
    REGION(t,     0, QA, KA, BwA, QB, KB, BwB, X0, X1);
    REGION(t + 1, 1, QB, KB, BwB, QA, KA, BwA, X1, X0);
  }
}

// ---------- phase 3: out = h + ys @ Wout^T  (in-place over ys==out) ----------

__global__ __launch_bounds__(256)
void srwm_proj(const float* __restrict__ h, const float* __restrict__ ys,
               const float* __restrict__ Wout, float* __restrict__ out) {
  __shared__ float ytile[32][256];  // 32 KB
  const int r0  = blockIdx.x * 32;
  const int tid = threadIdx.x;

  const float4* src = (const float4*)(ys + (size_t)r0 * 256);
  float4*       dst = (float4*)(&ytile[0][0]);
#pragma unroll
  for (int i = 0; i < 8; ++i) dst[tid + i * 256] = src[tid + i * 256];
  __syncthreads();

  float acc[32];
#pragma unroll
  for (int m = 0; m < 32; ++m) acc[m] = 0.f;

  const float* wrow = Wout + (size_t)tid * 256;
  for (int k = 0; k < 256; k += 4) {
    float4 w = *(const float4*)(wrow + k);
#pragma unroll
    for (int m = 0; m < 32; ++m) {
      float4 y4 = *(const float4*)(&ytile[m][k]);
      acc[m] = fmaf(w.x, y4.x,
               fmaf(w.y, y4.y,
               fmaf(w.z, y4.z,
               fmaf(w.w, y4.w, acc[m]))));
    }
  }

#pragma unroll
  for (int m = 0; m < 32; ++m) {
    int row = r0 + m;
    out[(size_t)row * 256 + tid] = h[(size_t)row * 256 + tid] + acc[m];
  }
}

// ---------- launcher ----------

extern "C" void kernel_launch(void* const* d_in, const int* in_sizes, int n_in,
                              void* d_out, int out_size, void* d_ws, size_t ws_size,
                              hipStream_t stream) {
  const float* h    = (const float*)d_in[0];
  const float* Wy0  = (const float*)d_in[1];
  const float* Wq0  = (const float*)d_in[2];
  const float* Wk0  = (const float*)d_in[3];
  const float* wb0  = (const float*)d_in[4];
  const float* Wout = (const float*)d_in[5];
  float* out = (float*)d_out;

  // d_out triple duty: x (phase1) -> progressively overwritten by y (phase2)
  // -> final output (phase3, in-place via LDS tile).
  srwm_xsm <<<SLEN * HSTRIDE / 256, 256, 0, stream>>>(h, out);
  srwm_scan<<<64, 256, 0, stream>>>(Wy0, Wq0, Wk0, wb0, out);
  srwm_proj<<<256, 256, 0, stream>>>(h, out, Wout, out);
}

// Round 6
// 568.798 us; speedup vs baseline: 2.2539x; 1.0043x over previous
//
#include <hip/hip_runtime.h>

#define DEV __device__ __forceinline__

// ---------- cross-lane helpers (all VALU, no LDS) ----------

template <int CTRL>
DEV float dppf(float x) {
  return __int_as_float(__builtin_amdgcn_update_dpp(
      0, __float_as_int(x), CTRL, 0xF, 0xF, true));
}

// Butterfly sum within each 32-lane half; result broadcast to all lanes of the half.
DEV float wsum32(float v) {
  v += dppf<0xB1>(v);   // xor1
  v += dppf<0x4E>(v);   // xor2
  v += dppf<0x141>(v);  // xor4 (row_half_mirror)
  v += dppf<0x140>(v);  // xor8 (row_mirror)
#if __has_builtin(__builtin_amdgcn_permlane16_swap)
  {
    auto p = __builtin_amdgcn_permlane16_swap(
        __float_as_uint(v), __float_as_uint(v), false, false);
    v = __uint_as_float(p[0]) + __uint_as_float(p[1]);  // v[l] + v[l^16]
  }
#else
  v += __shfl_xor(v, 16, 64);
#endif
  return v;
}

// v[l] + v[l^32] (combine the two half-row partial dots).
DEV float halfsum(float v) {
#if __has_builtin(__builtin_amdgcn_permlane32_swap)
  auto p = __builtin_amdgcn_permlane32_swap(
      __float_as_uint(v), __float_as_uint(v), false, false);
  return __uint_as_float(p[0]) + __uint_as_float(p[1]);
#else
  return v + __shfl_xor(v, 32, 64);
#endif
}

#define SLEN 1024
#define NH 8
#define DH 32
#define HSTRIDE 2048  // floats per timestep (B*NH*DH)

// ---------- phase 1: x = softmax32(h), staged into d_out ----------

__global__ __launch_bounds__(256)
void srwm_xsm(const float* __restrict__ h, float* __restrict__ x) {
  int i = blockIdx.x * 256 + threadIdx.x;
  float e = __expf(h[i]);
  x[i] = __fdividef(e, wsum32(e));  // 32-groups align with lane halves
}

// ---------- phase 2: the scan. One block (4 waves) per (b,h). ----------
// Wave w owns one matrix: 0:Wy 1:Wq 2:Wk 3:wb^T. Lane (r=lane&31, c0) holds
// cols c0..c0+15 of row r (w<3) or wb^T chunk wb[c0+j][r&3] (w==3).
//
// Deferred-update recurrence (identical math to R5):
// entering region T: regs hold q_{T-1},k_{T-1} chunks (QV,KV), B_{T-1}[w] (BW);
// W = W_{T-1}; preA = W_{T-1} x_T.
//
// KEY FIX vs R5: the barrier is LDS-only. The old asm "memory"-clobber barrier
// made the backend insert s_waitcnt vmcnt(0) each step, draining the in-flight
// x-prefetch AND w0's y-store (HBM retire) on the critical path every step.
// Here: sched_barrier pins, bare lgkmcnt(0) wait (no clobber), s_barrier.
// Global loads/stores stay in flight across steps; the compiler's counted
// vmcnt(N) covers prefetch consumption (stores are always younger).

#define BARRIER()                                        \
  do {                                                   \
    __builtin_amdgcn_sched_barrier(0);                   \
    asm volatile("s_waitcnt lgkmcnt(0)");                \
    __builtin_amdgcn_sched_barrier(0);                   \
    __builtin_amdgcn_s_barrier();                        \
    __builtin_amdgcn_sched_barrier(0);                   \
  } while (0)

#define REGION(T, P, QV, KV, BW, QN, KN, BN, XS, XP)                          \
  {                                                                           \
    /* ---- on-path: dv, d-matvec + s-dot (interleaved), u, a_T ---- */       \
    float dv[16];                                                             \
    _Pragma("unroll") for (int j = 0; j < 16; ++j) dv[j] = QV[j] - KV[j];     \
    float d0 = 0.f, d1 = 0.f, d2 = 0.f, d3 = 0.f, s0 = 0.f, s1 = 0.f;         \
    _Pragma("unroll") for (int j = 0; j < 16; j += 4) {                       \
      d0 = fmaf(W[j],     dv[j],     d0);                                     \
      d1 = fmaf(W[j + 1], dv[j + 1], d1);                                     \
      d2 = fmaf(W[j + 2], dv[j + 2], d2);                                     \
      d3 = fmaf(W[j + 3], dv[j + 3], d3);                                     \
      s0 = fmaf(KV[j],     XS[j],     s0);                                    \
      s1 = fmaf(KV[j + 1], XS[j + 1], s1);                                    \
      s0 = fmaf(KV[j + 2], XS[j + 2], s0);                                    \
      s1 = fmaf(KV[j + 3], XS[j + 3], s1);                                    \
    }                                                                         \
    float dsum = halfsum((d0 + d1) + (d2 + d3));                              \
    float sv   = halfsum(s0 + s1);                                            \
    float u  = BW * dsum;                                                     \
    float aA = fmaf(u, sv, preA);                                             \
    if (w == 0) {                                                             \
      if (lane < DH) xb[(size_t)(T) * HSTRIDE + lane] = aA;  /* y_T */        \
    } else if (w == 1) {                                                      \
      float e = __expf(aA); qs[P][r] = __fdividef(e, wsum32(e));              \
    } else if (w == 2) {                                                      \
      float e = __expf(aA); ks2[P][r] = __fdividef(e, wsum32(e));             \
    } else {                                                                  \
      float sg = __fdividef(1.f, 1.f + __expf(-aA));                          \
      if (lane < 4) bss[P][lane] = sg;                                        \
    }                                                                         \
    BARRIER();                                                                \
    /* ---- post-barrier: reads first (latency), reg-work under them ---- */  \
    _Pragma("unroll") for (int j = 0; j < 16; j += 4) {                       \
      *(float4*)&QN[j] = *(const float4*)&qs[P][c0 + j];                      \
      *(float4*)&KN[j] = *(const float4*)&ks2[P][c0 + j];                     \
    }                                                                         \
    BN = bss[P][w];                                                           \
    /* W <- W_T (uses OLD k = KV) */                                          \
    _Pragma("unroll") for (int j = 0; j < 16; ++j)                            \
      W[j] = fmaf(u, KV[j], W[j]);                                            \
    /* prefetch x_{T+2} into XS (XS consumed above; compiler renames) */      \
    int t2 = (T) + 2; if (t2 > SLEN - 1) t2 = SLEN - 1;                       \
    _Pragma("unroll") for (int j = 0; j < 16; j += 4)                         \
      *(float4*)&XS[j] = *(const float4*)(xb + (size_t)t2 * HSTRIDE + c0 + j);\
    /* preA = W_T x_{T+1} */                                                  \
    float p0 = 0.f, p1 = 0.f, p2 = 0.f, p3 = 0.f;                             \
    _Pragma("unroll") for (int j = 0; j < 16; j += 4) {                       \
      p0 = fmaf(W[j],     XP[j],     p0);                                     \
      p1 = fmaf(W[j + 1], XP[j + 1], p1);                                     \
      p2 = fmaf(W[j + 2], XP[j + 2], p2);                                     \
      p3 = fmaf(W[j + 3], XP[j + 3], p3);                                     \
    }                                                                         \
    preA = halfsum((p0 + p1) + (p2 + p3));                                    \
  }

__global__ __launch_bounds__(256, 1)
void srwm_scan(const float* __restrict__ Wy0, const float* __restrict__ Wq0,
               const float* __restrict__ Wk0, const float* __restrict__ wb0,
               float* xy) {
  __shared__ float qs[2][DH];
  __shared__ float ks2[2][DH];
  __shared__ float bss[2][4];

  const int bh   = blockIdx.x;        // 0..63
  const int hd   = bh & 7;
  const int w    = threadIdx.x >> 6;  // wave: 0..3
  const int lane = threadIdx.x & 63;
  const int r    = lane & 31;
  const int c0   = (lane >> 5) * 16;

  // ---- load this wave's matrix ----
  float W[16];
  if (w < 3) {
    const float* src = (w == 0) ? Wy0 : (w == 1) ? Wq0 : Wk0;
    const float* p = src + (hd * DH + r) * DH + c0;
#pragma unroll
    for (int j = 0; j < 16; j += 4) *(float4*)&W[j] = *(const float4*)(p + j);
  } else {
    const int kk = r & 3;
#pragma unroll
    for (int j = 0; j < 16; ++j) W[j] = wb0[(hd * DH + c0 + j) * 4 + kk];
  }

  float* xb = xy + bh * DH;  // x/y for this (b,h): element [t*HSTRIDE + j]

  // ---- prologue: X0 <- x_0, X1 <- x_1; q_{-1}=k_{-1}=0, B_{-1}=0 in regs;
  //      preA = W_0 x_0 (u_{-1}=0 so W_{-1} == W_0) ----
  float X0[16], X1[16];
#pragma unroll
  for (int j = 0; j < 16; j += 4) {
    *(float4*)&X0[j] = *(const float4*)(xb + c0 + j);
    *(float4*)&X1[j] = *(const float4*)(xb + HSTRIDE + c0 + j);
  }
  float p0 = 0.f, p1 = 0.f, p2 = 0.f, p3 = 0.f;
#pragma unroll
  for (int j = 0; j < 16; j += 4) {
    p0 = fmaf(W[j],     X0[j],     p0);
    p1 = fmaf(W[j + 1], X0[j + 1], p1);
    p2 = fmaf(W[j + 2], X0[j + 2], p2);
    p3 = fmaf(W[j + 3], X0[j + 3], p3);
  }
  float preA = halfsum((p0 + p1) + (p2 + p3));

  float QA[16], KA[16], QB[16], KB[16];
#pragma unroll
  for (int j = 0; j < 16; ++j) { QA[j] = 0.f; KA[j] = 0.f; }
  float BwA = 0.f, BwB = 0.f;

  __syncthreads();

  for (int t = 0; t < SLEN; t += 2) {
    REGION(t,     0, QA, KA, BwA, QB, KB, BwB, X0, X1);
    REGION(t + 1, 1, QB, KB, BwB, QA, KA, BwA, X1, X0);
  }
}

// ---------- phase 3: out = h + ys @ Wout^T  (in-place over ys==out) ----------

__global__ __launch_bounds__(256)
void srwm_proj(const float* __restrict__ h, const float* __restrict__ ys,
               const float* __restrict__ Wout, float* __restrict__ out) {
  __shared__ float ytile[32][256];  // 32 KB
  const int r0  = blockIdx.x * 32;
  const int tid = threadIdx.x;

  const float4* src = (const float4*)(ys + (size_t)r0 * 256);
  float4*       dst = (float4*)(&ytile[0][0]);
#pragma unroll
  for (int i = 0; i < 8; ++i) dst[tid + i * 256] = src[tid + i * 256];
  __syncthreads();

  float acc[32];
#pragma unroll
  for (int m = 0; m < 32; ++m) acc[m] = 0.f;

  const float* wrow = Wout + (size_t)tid * 256;
  for (int k = 0; k < 256; k += 4) {
    float4 w = *(const float4*)(wrow + k);
#pragma unroll
    for (int m = 0; m < 32; ++m) {
      float4 y4 = *(const float4*)(&ytile[m][k]);
      acc[m] = fmaf(w.x, y4.x,
               fmaf(w.y, y4.y,
               fmaf(w.z, y4.z,
               fmaf(w.w, y4.w, acc[m]))));
    }
  }

#pragma unroll
  for (int m = 0; m < 32; ++m) {
    int row = r0 + m;
    out[(size_t)row * 256 + tid] = h[(size_t)row * 256 + tid] + acc[m];
  }
}

// ---------- launcher ----------

extern "C" void kernel_launch(void* const* d_in, const int* in_sizes, int n_in,
                              void* d_out, int out_size, void* d_ws, size_t ws_size,
                              hipStream_t stream) {
  const float* h    = (const float*)d_in[0];
  const float* Wy0  = (const float*)d_in[1];
  const float* Wq0  = (const float*)d_in[2];
  const float* Wk0  = (const float*)d_in[3];
  const float* wb0  = (const float*)d_in[4];
  const float* Wout = (const float*)d_in[5];
  float* out = (float*)d_out;

  // d_out triple duty: x (phase1) -> progressively overwritten by y (phase2)
  // -> final output (phase3, in-place via LDS tile).
  srwm_xsm <<<SLEN * HSTRIDE / 256, 256, 0, stream>>>(h, out);
  srwm_scan<<<64, 256, 0, stream>>>(Wy0, Wq0, Wk0, wb0, out);
  srwm_proj<<<256, 256, 0, stream>>>(h, out, Wout, out);
}